// Round 7
// baseline (163.039 us; speedup 1.0000x reference)
//
#include <hip/hip_runtime.h>
#include <hip/hip_bf16.h>
#include <math.h>

// Cart2Polar: output[b,c,y,x] = bilinear_sample(grid_feat[b,c], gx(y,x), gy(y,x))
// ref_feat is fully overwritten by the reference's scatter -> unused.
// Shapes (fixed): grid_feat [4,64,480,480] f32, out [4,64,480,360] f32.
//
// R7 = R6 + pipeline restructure: prefetch gathers are issued AFTER the last
// __syncthreads of the iteration (hipcc drains vmcnt(0) at every s_barrier --
// the R5/R6 prefetch was dead on arrival). Between issue and consume there are
// now only nontemporal stores -> loads genuinely stay in flight.
// sched_barrier(0) pins the load cluster so regalloc can't re-serialize it.

#define BB 4
#define CC 64
#define HC 480
#define WC 480
#define HP 480
#define WP 360

#define TY 16
#define TX 16
#define BYT (HP / TY)                  // 30
#define BXT ((WP + TX - 1) / TX)       // 23 (last tile x>=360 lanes: computed, not stored)
#define CSPLIT 2
#define CCB (CC / CSPLIT)              // 32 channels per block
#define NWG (BB * BYT * BXT * CSPLIT)  // 5520 = 8 * 690
#define NXCD 8
#define CPX (NWG / NXCD)               // 690
#define CB 16                          // channels per LDS batch (2 batches/block)

typedef float f2a __attribute__((ext_vector_type(2), aligned(4)));

__global__ __launch_bounds__(256) void c2p_kernel(const float* __restrict__ g,
                                                  float* __restrict__ out) {
    __shared__ float lds[CB][TY][TX + 1];   // +1 pad: conflict-free scalar r/w

    // --- bijective chunked XCD swizzle (5520 % 8 == 0) ---
    const int bid = blockIdx.x;
    const int logical = (bid & (NXCD - 1)) * CPX + (bid >> 3);
    // channel-half fastest -> both halves of a tile stay on one XCD chunk
    const int h  = logical & (CSPLIT - 1);
    const int t1 = logical >> 1;
    const int xt = t1 % BXT;
    const int t2 = t1 / BXT;
    const int yt = t2 % BYT;
    const int b  = t2 / BYT;

    const int tid  = threadIdx.x;
    const int lane = tid & 63;
    const int w    = tid >> 6;
    // gather-phase mapping: wave = 16 consecutive y (radii) x 4 consecutive x
    const int ly = lane >> 2;                 // 0..15
    const int lx = (w << 2) | (lane & 3);     // 0..15
    const int y  = yt * TY + ly;
    const int x  = xt * TX + lx;              // may be >=360 in last tile (not stored)

    // polar grid math (matches reference, fp32)
    const float PI = 3.14159265358979323846f;
    float theta = PI - (float)x * (2.0f * PI / (float)WP);
    float r = ((float)HP - 0.5f - (float)y + 3.0f) * (1.0f / ((float)HP + 3.0f)) * ((float)WC * 0.5f);
    float s, c;
    __sincosf(theta, &s, &c);
    float index_x = r * c + (float)WC * 0.5f;
    float index_y = r * s + (float)WC * 0.5f;
    const float scale = (float)(WC - 1) / (float)WC;
    float gx = index_x * scale;
    float gy = index_y * scale;

    float x0f = floorf(gx);
    float y0f = floorf(gy);
    float wx1 = gx - x0f;
    float wy1 = gy - y0f;
    float wx0 = 1.0f - wx1;
    float wy0 = 1.0f - wy1;

    // proven in-bounds for this geometry: x0,y0 in [0,478] -> no clamp/validity
    const int x0 = (int)x0f;
    const int y0 = (int)y0f;

    const float w00 = wx0 * wy0;
    const float w10 = wx1 * wy0;
    const float w01 = wx0 * wy1;
    const float w11 = wx1 * wy1;

    const int o0 = y0 * WC + x0;     // row y0, cols (x0, x0+1) as one float2
    const int o1 = o0 + WC;          // row y0+1

    constexpr int HWc = HC * WC;
    constexpr int HWp = HP * WP;

    const float* __restrict__ base = g + ((size_t)b * CC + h * CCB) * HWc;

    // store-phase mapping: x-major, 16 rows x 64B per wave-store
    const int srow = tid >> 4;                // 0..15
    const int scol = tid & 15;                // 0..15
    const int sy = yt * TY + srow;
    const int sx = xt * TX + scol;
    const bool sok = (sx < WP);
    float* __restrict__ ob = out + ((size_t)b * CC + h * CCB) * HWp + (size_t)sy * WP + sx;

    // ---- software-pipelined channel batches (2 per block) ----
    f2a a0[CB], a1[CB];

    // prologue: issue batch 0's 32 paired gathers as one un-splittable cluster
#pragma unroll
    for (int j = 0; j < CB; ++j) {
        const float* __restrict__ p = base + (size_t)j * HWc;
        a0[j] = *(const f2a*)(p + o0);
        a1[j] = *(const f2a*)(p + o1);
    }
    __builtin_amdgcn_sched_barrier(0);

#pragma unroll
    for (int cb = 0; cb < CCB; cb += CB) {
        // consume current batch (counted vmcnt waits, FMA interleaves)
        float v[CB];
#pragma unroll
        for (int j = 0; j < CB; ++j)
            v[j] = a0[j].x * w00 + a0[j].y * w10 + a1[j].x * w01 + a1[j].y * w11;

        __syncthreads();                       // prior batch's LDS reads done
#pragma unroll
        for (int j = 0; j < CB; ++j)
            lds[j][ly][lx] = v[j];
        __syncthreads();

        // issue NEXT batch AFTER the last barrier: nothing between issue and
        // consume but the stores -> loads stay in flight (no vmcnt(0) drain).
        if (cb + CB < CCB) {
#pragma unroll
            for (int j = 0; j < CB; ++j) {
                const float* __restrict__ p = base + (size_t)(cb + CB + j) * HWc;
                a0[j] = *(const f2a*)(p + o0);
                a1[j] = *(const f2a*)(p + o1);
            }
            __builtin_amdgcn_sched_barrier(0);
        }

        if (sok) {
#pragma unroll
            for (int j = 0; j < CB; ++j)
                __builtin_nontemporal_store(lds[j][srow][scol], &ob[(size_t)(cb + j) * HWp]);
        }
    }
}

extern "C" void kernel_launch(void* const* d_in, const int* in_sizes, int n_in,
                              void* d_out, int out_size, void* d_ws, size_t ws_size,
                              hipStream_t stream) {
    const float* grid_feat = (const float*)d_in[0];
    float* out = (float*)d_out;
    c2p_kernel<<<NWG, 256, 0, stream>>>(grid_feat, out);
}

// Round 8
// 144.208 us; speedup vs baseline: 1.1306x; 1.1306x over previous
//
#include <hip/hip_runtime.h>
#include <hip/hip_bf16.h>
#include <math.h>

// Cart2Polar: output[b,c,y,x] = bilinear_sample(grid_feat[b,c], gx(y,x), gy(y,x))
// ref_feat is fully overwritten by the reference's scatter -> unused.
// Shapes (fixed): grid_feat [4,64,480,480] f32, out [4,64,480,360] f32.
//
// R8 = R7 minus the XCD-chunked swizzle. The chunked mapping assigned 15
// CONSECUTIVE yt values per XCD chunk -> outer-ring XCDs had ~2x the work of
// inner-ring XCDs (block cost ~ tile cartesian footprint ~ radius). Identity
// round-robin balances radii across XCDs; yt-major order dispatches the big
// outer tiles first (tail = tiny inner tiles). Cross-block reuse lost is only
// tile-boundary lines (~5%) — channel-split siblings share zero bytes.

#define BB 4
#define CC 64
#define HC 480
#define WC 480
#define HP 480
#define WP 360

#define TY 16
#define TX 16
#define BYT (HP / TY)                  // 30
#define BXT ((WP + TX - 1) / TX)       // 23 (last tile x>=360 lanes: computed, not stored)
#define CSPLIT 2
#define CCB (CC / CSPLIT)              // 32 channels per block
#define NWG (BB * BYT * BXT * CSPLIT)  // 5520
#define CB 16                          // channels per LDS batch (2 batches/block)

typedef float f2a __attribute__((ext_vector_type(2), aligned(4)));

__global__ __launch_bounds__(256) void c2p_kernel(const float* __restrict__ g,
                                                  float* __restrict__ out) {
    __shared__ float lds[CB][TY][TX + 1];   // +1 pad: conflict-free scalar r/w

    // identity mapping: h fastest, then xt, yt, b -> round-robin over XCDs
    // mixes radii evenly; outer (yt=0) tiles dispatch first per batch-b.
    const int logical = blockIdx.x;
    const int h  = logical & (CSPLIT - 1);
    const int t1 = logical >> 1;
    const int xt = t1 % BXT;
    const int t2 = t1 / BXT;
    const int yt = t2 % BYT;
    const int b  = t2 / BYT;

    const int tid  = threadIdx.x;
    const int lane = tid & 63;
    const int w    = tid >> 6;
    // gather-phase mapping: wave = 16 consecutive y (radii) x 4 consecutive x
    const int ly = lane >> 2;                 // 0..15
    const int lx = (w << 2) | (lane & 3);     // 0..15
    const int y  = yt * TY + ly;
    const int x  = xt * TX + lx;              // may be >=360 in last tile (not stored)

    // polar grid math (matches reference, fp32)
    const float PI = 3.14159265358979323846f;
    float theta = PI - (float)x * (2.0f * PI / (float)WP);
    float r = ((float)HP - 0.5f - (float)y + 3.0f) * (1.0f / ((float)HP + 3.0f)) * ((float)WC * 0.5f);
    float s, c;
    __sincosf(theta, &s, &c);
    float index_x = r * c + (float)WC * 0.5f;
    float index_y = r * s + (float)WC * 0.5f;
    const float scale = (float)(WC - 1) / (float)WC;
    float gx = index_x * scale;
    float gy = index_y * scale;

    float x0f = floorf(gx);
    float y0f = floorf(gy);
    float wx1 = gx - x0f;
    float wy1 = gy - y0f;
    float wx0 = 1.0f - wx1;
    float wy0 = 1.0f - wy1;

    // proven in-bounds for this geometry: x0,y0 in [0,478] -> no clamp/validity
    const int x0 = (int)x0f;
    const int y0 = (int)y0f;

    const float w00 = wx0 * wy0;
    const float w10 = wx1 * wy0;
    const float w01 = wx0 * wy1;
    const float w11 = wx1 * wy1;

    const int o0 = y0 * WC + x0;     // row y0, cols (x0, x0+1) as one float2
    const int o1 = o0 + WC;          // row y0+1

    constexpr int HWc = HC * WC;
    constexpr int HWp = HP * WP;

    const float* __restrict__ base = g + ((size_t)b * CC + h * CCB) * HWc;

    // store-phase mapping: x-major, 16 rows x 64B per wave-store
    const int srow = tid >> 4;                // 0..15
    const int scol = tid & 15;                // 0..15
    const int sy = yt * TY + srow;
    const int sx = xt * TX + scol;
    const bool sok = (sx < WP);
    float* __restrict__ ob = out + ((size_t)b * CC + h * CCB) * HWp + (size_t)sy * WP + sx;

    // ---- software-pipelined channel batches (2 per block) ----
    f2a a0[CB], a1[CB];

    // prologue: issue batch 0's 32 paired gathers as one un-splittable cluster
#pragma unroll
    for (int j = 0; j < CB; ++j) {
        const float* __restrict__ p = base + (size_t)j * HWc;
        a0[j] = *(const f2a*)(p + o0);
        a1[j] = *(const f2a*)(p + o1);
    }
    __builtin_amdgcn_sched_barrier(0);

#pragma unroll
    for (int cb = 0; cb < CCB; cb += CB) {
        // consume current batch (counted vmcnt waits, FMA interleaves)
        float v[CB];
#pragma unroll
        for (int j = 0; j < CB; ++j)
            v[j] = a0[j].x * w00 + a0[j].y * w10 + a1[j].x * w01 + a1[j].y * w11;

        __syncthreads();                       // prior batch's LDS reads done
#pragma unroll
        for (int j = 0; j < CB; ++j)
            lds[j][ly][lx] = v[j];
        __syncthreads();

        // issue NEXT batch AFTER the last barrier: nothing between issue and
        // consume but the stores -> loads stay in flight (no vmcnt(0) drain).
        if (cb + CB < CCB) {
#pragma unroll
            for (int j = 0; j < CB; ++j) {
                const float* __restrict__ p = base + (size_t)(cb + CB + j) * HWc;
                a0[j] = *(const f2a*)(p + o0);
                a1[j] = *(const f2a*)(p + o1);
            }
            __builtin_amdgcn_sched_barrier(0);
        }

        if (sok) {
#pragma unroll
            for (int j = 0; j < CB; ++j)
                __builtin_nontemporal_store(lds[j][srow][scol], &ob[(size_t)(cb + j) * HWp]);
        }
    }
}

extern "C" void kernel_launch(void* const* d_in, const int* in_sizes, int n_in,
                              void* d_out, int out_size, void* d_ws, size_t ws_size,
                              hipStream_t stream) {
    const float* grid_feat = (const float*)d_in[0];
    float* out = (float*)d_out;
    c2p_kernel<<<NWG, 256, 0, stream>>>(grid_feat, out);
}

// Round 9
// 132.703 us; speedup vs baseline: 1.2286x; 1.0867x over previous
//
#include <hip/hip_runtime.h>
#include <hip/hip_bf16.h>
#include <math.h>

// Cart2Polar: output[b,c,y,x] = bilinear_sample(grid_feat[b,c], gx(y,x), gy(y,x))
// ref_feat is fully overwritten by the reference's scatter -> unused.
// Shapes (fixed): grid_feat [4,64,480,480] f32, out [4,64,480,360] f32.
//
// R9: force MLP=32 with asm-volatile gather cluster. Three rounds of source-
// level pipelining failed identically (VGPR stuck ~44): hipcc sinks plain
// loads to first use at IR level; sched_barrier can't stop that. asm volatile
// loads have fixed program order and opaque results -> 32 loads in flight,
// 64 result VGPRs live. Explicit s_waitcnt vmcnt(0) + sched_barrier(0) before
// consume (compiler doesn't track vmcnt of asm loads — rule #18).
// Structure simplified: 16 ch/block (CSPLIT=4), single batch, one barrier.

#define BB 4
#define CC 64
#define HC 480
#define WC 480
#define HP 480
#define WP 360

#define TY 16
#define TX 16
#define BYT (HP / TY)                  // 30
#define BXT ((WP + TX - 1) / TX)       // 23 (last tile x>=360 lanes: computed, not stored)
#define CSPLIT 4
#define CCB (CC / CSPLIT)              // 16 channels per block
#define NWG (BB * BYT * BXT * CSPLIT)  // 11040
#define CB 16                          // = CCB, single LDS batch

typedef float f2a __attribute__((ext_vector_type(2), aligned(8)));

__global__ __launch_bounds__(256) void c2p_kernel(const float* __restrict__ g,
                                                  float* __restrict__ out) {
    __shared__ float lds[CB][TY][TX + 1];   // +1 pad: conflict-free scalar r/w

    // identity mapping: round-robin over XCDs mixes radii (load balance, R8 win)
    const int logical = blockIdx.x;
    const int h  = logical & (CSPLIT - 1);
    const int t1 = logical >> 2;
    const int xt = t1 % BXT;
    const int t2 = t1 / BXT;
    const int yt = t2 % BYT;
    const int b  = t2 / BYT;

    const int tid  = threadIdx.x;
    const int lane = tid & 63;
    const int w    = tid >> 6;
    // gather-phase mapping: wave = 16 consecutive y (radii) x 4 consecutive x
    const int ly = lane >> 2;                 // 0..15
    const int lx = (w << 2) | (lane & 3);     // 0..15
    const int y  = yt * TY + ly;
    const int x  = xt * TX + lx;              // may be >=360 in last tile (not stored)

    // polar grid math (matches reference, fp32)
    const float PI = 3.14159265358979323846f;
    float theta = PI - (float)x * (2.0f * PI / (float)WP);
    float r = ((float)HP - 0.5f - (float)y + 3.0f) * (1.0f / ((float)HP + 3.0f)) * ((float)WC * 0.5f);
    float s, c;
    __sincosf(theta, &s, &c);
    float index_x = r * c + (float)WC * 0.5f;
    float index_y = r * s + (float)WC * 0.5f;
    const float scale = (float)(WC - 1) / (float)WC;
    float gx = index_x * scale;
    float gy = index_y * scale;

    float x0f = floorf(gx);
    float y0f = floorf(gy);
    float wx1 = gx - x0f;
    float wy1 = gy - y0f;
    float wx0 = 1.0f - wx1;
    float wy0 = 1.0f - wy1;

    // proven in-bounds for this geometry: x0,y0 in [0,478] -> no clamp/validity
    const int x0 = (int)x0f;
    const int y0 = (int)y0f;

    const float w00 = wx0 * wy0;
    const float w10 = wx1 * wy0;
    const float w01 = wx0 * wy1;
    const float w11 = wx1 * wy1;

    const int o0 = y0 * WC + x0;     // row y0, cols (x0, x0+1) as one float2
    const int o1 = o0 + WC;          // row y0+1

    constexpr int HWc = HC * WC;
    constexpr int HWp = HP * WP;

    const float* __restrict__ base = g + ((size_t)b * CC + h * CCB) * HWc;

    // store-phase mapping: x-major, 16 rows x 64B per wave-store
    const int srow = tid >> 4;                // 0..15
    const int scol = tid & 15;                // 0..15
    const int sy = yt * TY + srow;
    const int sx = xt * TX + scol;
    const bool sok = (sx < WP);
    float* __restrict__ ob = out + ((size_t)b * CC + h * CCB) * HWp + (size_t)sy * WP + sx;

    // ---- asm-forced gather cluster: 32 dwordx2 loads, all in flight ----
    f2a a0[CB], a1[CB];
#pragma unroll
    for (int j = 0; j < CB; ++j) {
        const float* p0 = base + (size_t)j * HWc + o0;
        const float* p1 = base + (size_t)j * HWc + o1;
        asm volatile("global_load_dwordx2 %0, %1, off"
                     : "=v"(a0[j]) : "v"(p0));
        asm volatile("global_load_dwordx2 %0, %1, off"
                     : "=v"(a1[j]) : "v"(p1));
    }
    // compiler doesn't track vmcnt for asm loads: drain, then fence scheduling
    asm volatile("s_waitcnt vmcnt(0)" ::: "memory");
    __builtin_amdgcn_sched_barrier(0);

    float v[CB];
#pragma unroll
    for (int j = 0; j < CB; ++j)
        v[j] = a0[j].x * w00 + a0[j].y * w10 + a1[j].x * w01 + a1[j].y * w11;

#pragma unroll
    for (int j = 0; j < CB; ++j)
        lds[j][ly][lx] = v[j];
    __syncthreads();

    if (sok) {
#pragma unroll
        for (int j = 0; j < CB; ++j)
            __builtin_nontemporal_store(lds[j][srow][scol], &ob[(size_t)j * HWp]);
    }
}

extern "C" void kernel_launch(void* const* d_in, const int* in_sizes, int n_in,
                              void* d_out, int out_size, void* d_ws, size_t ws_size,
                              hipStream_t stream) {
    const float* grid_feat = (const float*)d_in[0];
    float* out = (float*)d_out;
    c2p_kernel<<<NWG, 256, 0, stream>>>(grid_feat, out);
}

// Round 10
// 131.920 us; speedup vs baseline: 1.2359x; 1.0059x over previous
//
#include <hip/hip_runtime.h>
#include <hip/hip_bf16.h>
#include <math.h>

// Cart2Polar: output[b,c,y,x] = bilinear_sample(grid_feat[b,c], gx(y,x), gy(y,x))
// ref_feat is fully overwritten by the reference's scatter -> unused.
// Shapes (fixed): grid_feat [4,64,480,480] f32, out [4,64,480,360] f32.
//
// R10 = R9 with the spill fixed so the MLP=32 experiment actually runs:
//  - __launch_bounds__(256,2): VGPR cap 256 (R9's default cap made the
//    allocator spill all 64 asm-result regs to scratch -> VGPR_Count=40).
//  - counted vmcnt drain: consume channel j after s_waitcnt vmcnt(2*(15-j)),
//    so FMA+LDS-write of early channels overlaps the still-outstanding loads.
//    sched_barrier(0) after each waitcnt: asm loads have no HW interlock and
//    plain FMAs would otherwise be free to hoist above the waitcnt (rule #18).

#define BB 4
#define CC 64
#define HC 480
#define WC 480
#define HP 480
#define WP 360

#define TY 16
#define TX 16
#define BYT (HP / TY)                  // 30
#define BXT ((WP + TX - 1) / TX)       // 23 (last tile x>=360 lanes: computed, not stored)
#define CSPLIT 4
#define CCB (CC / CSPLIT)              // 16 channels per block
#define NWG (BB * BYT * BXT * CSPLIT)  // 11040
#define CB 16                          // = CCB, single LDS batch

typedef float f2a __attribute__((ext_vector_type(2), aligned(8)));

__global__ __launch_bounds__(256, 2) void c2p_kernel(const float* __restrict__ g,
                                                     float* __restrict__ out) {
    __shared__ float lds[CB][TY][TX + 1];   // +1 pad: conflict-free scalar r/w

    // identity mapping: round-robin over XCDs mixes radii (load balance, R8 win)
    const int logical = blockIdx.x;
    const int h  = logical & (CSPLIT - 1);
    const int t1 = logical >> 2;
    const int xt = t1 % BXT;
    const int t2 = t1 / BXT;
    const int yt = t2 % BYT;
    const int b  = t2 / BYT;

    const int tid  = threadIdx.x;
    const int lane = tid & 63;
    const int w    = tid >> 6;
    // gather-phase mapping: wave = 16 consecutive y (radii) x 4 consecutive x
    const int ly = lane >> 2;                 // 0..15
    const int lx = (w << 2) | (lane & 3);     // 0..15
    const int y  = yt * TY + ly;
    const int x  = xt * TX + lx;              // may be >=360 in last tile (not stored)

    // polar grid math (matches reference, fp32)
    const float PI = 3.14159265358979323846f;
    float theta = PI - (float)x * (2.0f * PI / (float)WP);
    float r = ((float)HP - 0.5f - (float)y + 3.0f) * (1.0f / ((float)HP + 3.0f)) * ((float)WC * 0.5f);
    float s, c;
    __sincosf(theta, &s, &c);
    float index_x = r * c + (float)WC * 0.5f;
    float index_y = r * s + (float)WC * 0.5f;
    const float scale = (float)(WC - 1) / (float)WC;
    float gx = index_x * scale;
    float gy = index_y * scale;

    float x0f = floorf(gx);
    float y0f = floorf(gy);
    float wx1 = gx - x0f;
    float wy1 = gy - y0f;
    float wx0 = 1.0f - wx1;
    float wy0 = 1.0f - wy1;

    // proven in-bounds for this geometry: x0,y0 in [0,478] -> no clamp/validity
    const int x0 = (int)x0f;
    const int y0 = (int)y0f;

    const float w00 = wx0 * wy0;
    const float w10 = wx1 * wy0;
    const float w01 = wx0 * wy1;
    const float w11 = wx1 * wy1;

    const int o0 = y0 * WC + x0;     // row y0, cols (x0, x0+1) as one float2
    const int o1 = o0 + WC;          // row y0+1

    constexpr int HWc = HC * WC;
    constexpr int HWp = HP * WP;

    const float* __restrict__ base = g + ((size_t)b * CC + h * CCB) * HWc;

    // store-phase mapping: x-major, 16 rows x 64B per wave-store
    const int srow = tid >> 4;                // 0..15
    const int scol = tid & 15;                // 0..15
    const int sy = yt * TY + srow;
    const int sx = xt * TX + scol;
    const bool sok = (sx < WP);
    float* __restrict__ ob = out + ((size_t)b * CC + h * CCB) * HWp + (size_t)sy * WP + sx;

    // ---- asm-forced gather cluster: 32 dwordx2 loads, all in flight ----
    f2a a0[CB], a1[CB];
#pragma unroll
    for (int j = 0; j < CB; ++j) {
        const float* p0 = base + (size_t)j * HWc + o0;
        const float* p1 = base + (size_t)j * HWc + o1;
        asm volatile("global_load_dwordx2 %0, %1, off"
                     : "=v"(a0[j]) : "v"(p0));
        asm volatile("global_load_dwordx2 %0, %1, off"
                     : "=v"(a1[j]) : "v"(p1));
    }

    // ---- counted drain: consume channel j while 2*(CB-1-j) loads still fly ----
#pragma unroll
    for (int j = 0; j < CB; ++j) {
        asm volatile("s_waitcnt vmcnt(%0)" :: "i"(2 * (CB - 1 - j)) : "memory");
        __builtin_amdgcn_sched_barrier(0);
        lds[j][ly][lx] = a0[j].x * w00 + a0[j].y * w10
                       + a1[j].x * w01 + a1[j].y * w11;
    }
    __syncthreads();

    if (sok) {
#pragma unroll
        for (int j = 0; j < CB; ++j)
            __builtin_nontemporal_store(lds[j][srow][scol], &ob[(size_t)j * HWp]);
    }
}

extern "C" void kernel_launch(void* const* d_in, const int* in_sizes, int n_in,
                              void* d_out, int out_size, void* d_ws, size_t ws_size,
                              hipStream_t stream) {
    const float* grid_feat = (const float*)d_in[0];
    float* out = (float*)d_out;
    c2p_kernel<<<NWG, 256, 0, stream>>>(grid_feat, out);
}